// Round 5
// baseline (436.043 us; speedup 1.0000x reference)
//
#include <hip/hip_runtime.h>

#define MARGIN   0.3f
#define S_SCALE  15.0f
#define LAMDA    2.0f
#define NB       8192
#define NC       10000
#define MAXLOGIT 15.0f   // logits = 15*costh, costh in [0,1] -> fixed, safe shift

// One WAVE per row (4 rows per 256-thread block, 2048 blocks = 8 blocks/CU:
// whole grid co-resident, no dispatch tail). No LDS, no __syncthreads.
// 2500 float4 per row / 64 lanes = 39 full stride-64 loads per lane plus a
// 4-lane tail (idx 2496..2499). All trips compile-time; wave-only shuffle
// reduce; lane 0 patches the margin-adjusted target term and writes the row
// loss.
__global__ __launch_bounds__(256, 4) void dam_row_loss(const float* __restrict__ costh,
                                                       const int* __restrict__ label,
                                                       float* __restrict__ row_loss) {
    const int wave = threadIdx.x >> 6;            // 0..3
    const int lane = threadIdx.x & 63;
    const int row  = (blockIdx.x << 2) | wave;    // 2048*4 = 8192 rows
    const float* __restrict__ rowp = costh + (size_t)row * NC;
    const float4* __restrict__ rp4 = (const float4*)rowp;   // rows are 16B-aligned (40000 B)

    // Early broadcast loads: label[row] then the target cosine. Dependent
    // chain (~2 HBM latencies) hides under the 39-load bulk stream below.
    const int lbl = label[row];
    const float cos_t = rowp[lbl];

    float s = 0.0f;
    #pragma unroll
    for (int j = 0; j < 39; ++j) {
        float4 v = rp4[lane + (j << 6)];          // idx <= 63 + 38*64 = 2495
        s += __expf(fmaf(S_SCALE, v.x, -MAXLOGIT));
        s += __expf(fmaf(S_SCALE, v.y, -MAXLOGIT));
        s += __expf(fmaf(S_SCALE, v.z, -MAXLOGIT));
        s += __expf(fmaf(S_SCALE, v.w, -MAXLOGIT));
    }
    if (lane < 4) {                               // tail: float4 idx 2496..2499
        float4 v = rp4[2496 + lane];
        s += __expf(fmaf(S_SCALE, v.x, -MAXLOGIT));
        s += __expf(fmaf(S_SCALE, v.y, -MAXLOGIT));
        s += __expf(fmaf(S_SCALE, v.z, -MAXLOGIT));
        s += __expf(fmaf(S_SCALE, v.w, -MAXLOGIT));
    }

    // wave64 shuffle reduce — no cross-wave combine needed
    #pragma unroll
    for (int off = 32; off > 0; off >>= 1)
        s += __shfl_down(s, off, 64);

    if (lane == 0) {
        float tot = s;
        const float delta = (MARGIN / LAMDA) * __expf(1.0f - cos_t);
        const float t_logit = S_SCALE * (cos_t - delta);           // modified target logit
        // swap original target term for the margin-adjusted one
        tot = tot - __expf(fmaf(S_SCALE, cos_t, -MAXLOGIT)) + __expf(t_logit - MAXLOGIT);
        const float lse = MAXLOGIT + __logf(tot);
        row_loss[row] = lse - t_logit;                             // -logp[target]
    }
}

// 8192 floats -> scalar mean. Single block; compile-time 32-trip loop, same
// deterministic add order every run.
__global__ __launch_bounds__(256) void dam_reduce(const float* __restrict__ row_loss,
                                                  float* __restrict__ out) {
    const int tid = threadIdx.x;
    float s = 0.0f;
    #pragma unroll
    for (int i = tid; i < NB; i += 256) s += row_loss[i];
    #pragma unroll
    for (int off = 32; off > 0; off >>= 1)
        s += __shfl_down(s, off, 64);
    __shared__ float wsum[4];
    if ((tid & 63) == 0) wsum[tid >> 6] = s;
    __syncthreads();
    if (tid == 0) out[0] = (wsum[0] + wsum[1] + wsum[2] + wsum[3]) * (1.0f / (float)NB);
}

extern "C" void kernel_launch(void* const* d_in, const int* in_sizes, int n_in,
                              void* d_out, int out_size, void* d_ws, size_t ws_size,
                              hipStream_t stream) {
    const float* costh = (const float*)d_in[0];
    const int*   label = (const int*)d_in[1];
    float* out = (float*)d_out;
    float* row_loss = (float*)d_ws;  // 8192 floats = 32 KB scratch

    dam_row_loss<<<NB / 4, 256, 0, stream>>>(costh, label, row_loss);
    dam_reduce<<<1, 256, 0, stream>>>(row_loss, out);
}